// Round 2
// baseline (1099.780 us; speedup 1.0000x reference)
//
#include <hip/hip_runtime.h>
#include <hip/hip_bf16.h>

typedef unsigned short u16;
typedef __attribute__((ext_vector_type(8))) short short8;
typedef __attribute__((ext_vector_type(4))) float floatx4;
typedef __attribute__((ext_vector_type(4), aligned(4))) float floatx4u;  // 4B-aligned vector load
typedef __attribute__((ext_vector_type(4))) unsigned int uint4v;

#define B_ 32
#define S_ 197
#define D_ 1024
#define H_ 16
#define DK_ 64
#define BH_ 512
#define SP_ 208   // S padded to 13*16 (row tiles)
#define TP_ 224   // S padded to 7*32 (K-dim tiles)
#define TPP_ 232  // TP_ padded for LDS bank spread (464B rows, 16B-aligned, 2-way only)
#define M_ 6304   // B*S
#define XSZ_ ((size_t)M_*D_)        // 6,455,296 elems per x
#define WSZ_W ((size_t)D_*D_)       // 1,048,576 elems per weight

// workspace layout (bf16 element offsets)
#define KSZ ((size_t)BH_*SP_*DK_)   // 6,815,744
#define VSZ ((size_t)BH_*DK_*TP_)   // 7,340,032
#define CSZ ((size_t)BH_*SP_*TP_)   // 23,855,104
#define K0_OFF  ((size_t)0)
#define K1_OFF  (KSZ)
#define VT0_OFF (2*KSZ)
#define VT1_OFF (2*KSZ + VSZ)
#define F0_OFF  (2*KSZ + 2*VSZ)
#define F1_OFF  (3*KSZ + 2*VSZ)
#define COMB_OFF (4*KSZ + 2*VSZ)
#define WOT_OFF  (4*KSZ + 2*VSZ + CSZ)
#define BIAS_OFF (WOT_OFF + (size_t)D_*TP_)   // bk0|bk1|bv0|bv1|bo, 1024 each, bf16
#define WS_ELEMS (BIAS_OFF + 5*1024)

// bf16 staging of inputs lives in the COMB region (dead until comb_kernel runs)
#define XB_OFF  (COMB_OFF)
#define WB_OFF  (COMB_OFF + 2*XSZ_)

// d_out layout (elements of the output dtype): out | a0 | a1
#define OUT_SZ ((size_t)BH_*S_*D_)   // 103,284,736
#define A_SZ   ((size_t)BH_*S_*S_)   // 19,870,208

__device__ __forceinline__ float bf2f(u16 v) {
    unsigned u = ((unsigned)v) << 16;
    return __builtin_bit_cast(float, u);
}
__device__ __forceinline__ u16 f2bf(float f) {
    unsigned u = __builtin_bit_cast(unsigned, f);
    u += 0x7FFFu + ((u >> 16) & 1u);   // RNE
    return (u16)(u >> 16);
}
__device__ __forceinline__ floatx4 mfma16(short8 a, short8 b, floatx4 c) {
    return __builtin_amdgcn_mfma_f32_16x16x32_bf16(a, b, c, 0, 0, 0);
}
// async global->LDS, 16B per lane; lds dest is wave-uniform base + lane*16
__device__ __forceinline__ void gl_lds16(const u16* g, u16* l) {
    __builtin_amdgcn_global_load_lds(
        (const __attribute__((address_space(1))) void*)(g),
        (__attribute__((address_space(3))) void*)(l), 16, 0, 0);
}

// Runtime input-dtype detection (see previous rounds): deterministic, cheap.
__device__ __forceinline__ int detect_f32(const u16* __restrict__ x0raw) {
    int lane = threadIdx.x & 63;
    unsigned h = x0raw[2*lane];
    unsigned e = (h >> 7) & 0xFFu;
    int ext = (e < 0x30u) | (e > 0x4Fu);
    unsigned long long m = __ballot(ext);
    return __popcll(m) > 16;
}

// dtype-flexible element accessors
__device__ __forceinline__ u16 loadBF(const void* p, size_t off, int is32) {
    return is32 ? f2bf(((const float*)p)[off]) : ((const u16*)p)[off];
}
__device__ __forceinline__ void storeF(void* p, size_t off, float v, int is32) {
    if (is32) ((float*)p)[off] = v; else ((u16*)p)[off] = f2bf(v);
}
// 8 contiguous elements -> bf16 bits (aligned: off multiple of 8)
__device__ __forceinline__ short8 load8(const void* p, size_t off, int is32) {
    short8 r;
    if (is32) {
        const float* f = (const float*)p + off;
        floatx4 a = *(const floatx4*)f;
        floatx4 b = *(const floatx4*)(f + 4);
        r[0]=(short)f2bf(a[0]); r[1]=(short)f2bf(a[1]);
        r[2]=(short)f2bf(a[2]); r[3]=(short)f2bf(a[3]);
        r[4]=(short)f2bf(b[0]); r[5]=(short)f2bf(b[1]);
        r[6]=(short)f2bf(b[2]); r[7]=(short)f2bf(b[3]);
    } else {
        r = *(const short8*)((const u16*)p + off);
    }
    return r;
}

// ---------------- prep: wot zero-padded; zero K/Vt pads; biases; bf16-convert inputs
__global__ __launch_bounds__(256) void prep_kernel(
    const void* __restrict__ wo,
    const void* __restrict__ bk0, const void* __restrict__ bk1,
    const void* __restrict__ bv0, const void* __restrict__ bv1,
    const void* __restrict__ bo,
    const void* __restrict__ x0, const void* __restrict__ x1,
    const void* __restrict__ wk0, const void* __restrict__ wk1,
    const void* __restrict__ wv0, const void* __restrict__ wv1,
    u16* __restrict__ ws) {
    int is32 = detect_f32((const u16*)x0);
    int i = blockIdx.x * 256 + threadIdx.x;
    if (i < D_*TP_) {
        int d = i / TP_, t = i - d*TP_;
        ws[WOT_OFF + i] = (t < S_) ? loadBF(wo, (size_t)d*S_ + t, is32) : (u16)0;
    }
    const int KP = BH_*(SP_-S_)*DK_;   // 360448
    if (i < KP) {
        int bh = i / ((SP_-S_)*DK_);
        int r  = i - bh*((SP_-S_)*DK_);
        int s  = S_ + r / DK_;
        int dk = r % DK_;
        size_t o = ((size_t)bh*SP_ + s)*DK_ + dk;
        ws[K0_OFF + o] = 0; ws[K1_OFF + o] = 0;
    }
    const int VP = BH_*DK_*(TP_-S_);   // 884736
    if (i < VP) {
        int bh = i / (DK_*(TP_-S_));
        int r  = i - bh*(DK_*(TP_-S_));
        int dk = r / (TP_-S_);
        int t  = S_ + r % (TP_-S_);
        size_t o = ((size_t)bh*DK_ + dk)*TP_ + t;
        ws[VT0_OFF + o] = 0; ws[VT1_OFF + o] = 0;
    }
    if (i < 5*1024) {
        int which = i >> 10, j = i & 1023;
        const void* src = (which==0) ? bk0 : (which==1) ? bk1
                        : (which==2) ? bv0 : (which==3) ? bv1 : bo;
        ws[BIAS_OFF + i] = loadBF(src, j, is32);
    }
    // grid-stride bf16 conversion: 2*XSZ_ x-elems + 4*WSZ_W weight-elems, 8 at a time
    const size_t NCH = (2*XSZ_ + 4*WSZ_W) / 8;   // 2,138,112 chunks
    for (size_t c = (size_t)blockIdx.x*256 + threadIdx.x; c < NCH;
         c += (size_t)gridDim.x*256) {
        size_t e = c * 8;
        const void* src; size_t soff;
        if (e < 2*XSZ_) {
            src = (e < XSZ_) ? x0 : x1;
            soff = (e < XSZ_) ? e : e - XSZ_;
        } else {
            size_t r = e - 2*XSZ_;
            int z = (int)(r >> 20);            // WSZ_W = 2^20
            src = (z==0) ? wk0 : (z==1) ? wk1 : (z==2) ? wv0 : wv1;
            soff = r & (WSZ_W - 1);
        }
        *(short8*)&ws[XB_OFF + e] = load8(src, soff, is32);
    }
}

// ---------------- projections: C = x@W^T + b -> K [bh][208][64] or Vt [bh][64][224]
// m97 structure: global_load_lds(16B) staging from pre-converted bf16, 2-barrier loop.
__global__ __launch_bounds__(256) void proj_kernel(u16* __restrict__ ws)
{
    __shared__ __align__(16) u16 lA[128*64];
    __shared__ __align__(16) u16 lB[128*64];
    int z = blockIdx.z;
    const u16* X = ws + XB_OFF + (size_t)(z & 1)*XSZ_;
    const u16* W = ws + WB_OFF + (size_t)z*WSZ_W;
    u16* dst = ws + ((z==0) ? K0_OFF : (z==1) ? K1_OFF : (z==2) ? VT0_OFF : VT1_OFF);
    int m0 = blockIdx.x * 128, n0 = blockIdx.y * 128;
    int tid = threadIdx.x;
    int w = tid >> 6, lane = tid & 63, q = lane >> 4, l15 = lane & 15;
    int wm = (w >> 1) * 64, wn = (w & 1) * 64;

    floatx4 acc[4][4];
    #pragma unroll
    for (int a = 0; a < 4; a++)
        #pragma unroll
        for (int b = 0; b < 4; b++) acc[a][b] = (floatx4){0.f,0.f,0.f,0.f};

    for (int kk = 0; kk < D_; kk += 64) {
        __syncthreads();
        #pragma unroll
        for (int it = 0; it < 4; it++) {
            int c = it*256 + w*64 + lane;   // chunk of 8 elems; lane-linear = LDS-linear
            int r = c >> 3, cc = c & 7;
            int m = m0 + r; if (m > M_-1) m = M_-1;
            gl_lds16(X + (size_t)m*D_ + kk + cc*8,        &lA[(it*256 + w*64)*8]);
            gl_lds16(W + (size_t)(n0 + r)*D_ + kk + cc*8, &lB[(it*256 + w*64)*8]);
        }
        __syncthreads();   // drains vmcnt before ds_read
        #pragma unroll
        for (int kc = 0; kc < 2; kc++) {
            short8 af[4], bf[4];
            #pragma unroll
            for (int mi = 0; mi < 4; mi++)
                af[mi] = *(const short8*)&lA[(wm + mi*16 + l15)*64 + kc*32 + q*8];
            #pragma unroll
            for (int ni = 0; ni < 4; ni++)
                bf[ni] = *(const short8*)&lB[(wn + ni*16 + l15)*64 + kc*32 + q*8];
            #pragma unroll
            for (int mi = 0; mi < 4; mi++)
                #pragma unroll
                for (int ni = 0; ni < 4; ni++)
                    acc[mi][ni] = mfma16(af[mi], bf[ni], acc[mi][ni]);
        }
    }
    #pragma unroll
    for (int ni = 0; ni < 4; ni++) {
        int n = n0 + wn + ni*16 + l15;
        float bv = bf2f(ws[BIAS_OFF + (size_t)z*1024 + n]);
        int h = n >> 6, dk = n & 63;
        #pragma unroll
        for (int mi = 0; mi < 4; mi++)
            #pragma unroll
            for (int r = 0; r < 4; r++) {
                int m = m0 + wm + mi*16 + q*4 + r;
                if (m < M_) {
                    int b = m / S_;
                    int s = m - b * S_;
                    int bh = b * H_ + h;
                    size_t o = (z < 2) ? (((size_t)bh*SP_ + s)*DK_ + dk)
                                       : (((size_t)bh*DK_ + dk)*TP_ + s);
                    dst[o] = f2bf(acc[mi][ni][r] + bv);
                }
            }
    }
}

// ---------------- fused scores+softmax+AV:
//   a_dir = softmax_rows(Ka @ Kb^T * scale) -> d_out (f32/bf16)
//   f_dir = a_dir @ V_dir -> ws F (bf16), P routed through per-wave LDS tile.
// LDS: lKb XOR-swizzled (bank-conflict-free ds_read_b128), lV/lP padded rows.
__global__ __launch_bounds__(256) void attn_av_kernel(u16* __restrict__ ws,
                                                      void* __restrict__ dout,
                                                      const u16* __restrict__ x0det) {
    __shared__ __align__(16) u16 lKb[SP_*DK_];      // 26.0 KB, XOR-swizzled
    __shared__ __align__(16) u16 lV[DK_*TPP_];      // 29.0 KB, padded rows
    __shared__ __align__(16) u16 lP[4][16*TPP_];    // 29.0 KB, per-wave P tile
    int is32 = detect_f32(x0det);
    int bh = blockIdx.x, dir = blockIdx.y;
    const u16* Ka = ws + (dir ? K1_OFF : K0_OFF) + (size_t)bh*SP_*DK_;
    const u16* Kb = ws + (dir ? K0_OFF : K1_OFF) + (size_t)bh*SP_*DK_;
    const u16* Vt = ws + (dir ? VT1_OFF : VT0_OFF) + (size_t)bh*DK_*TP_;
    u16* fO = ws + (dir ? F1_OFF : F0_OFF) + (size_t)bh*SP_*DK_;
    size_t aBase = OUT_SZ + (size_t)dir*A_SZ + (size_t)bh*S_*S_;
    int tid = threadIdx.x;
    // stage Kb with XOR swizzle: chunk i (row=i>>3, c=i&7) -> row*8 + (c ^ (row&7))
    for (int i = tid; i < SP_*8; i += 256)
        ((uint4v*)lKb)[(i & ~7) | ((i ^ (i >> 3)) & 7)] = ((const uint4v*)Kb)[i];
    // stage V into padded rows: src 28 chunks/row -> dst 29 chunks/row
    for (int i = tid; i < DK_*28; i += 256) {
        int row = i / 28, c = i - row*28;
        ((uint4v*)lV)[row*29 + c] = ((const uint4v*)Vt)[i];
    }
    __syncthreads();
    int w = tid>>6, lane = tid&63, q = lane>>4, l15 = lane&15;
    u16* lPw = &lP[w][0];
    const float scale = 0.125f;
    for (int rt = w; rt < 13; rt += 4) {
        // ---- scores: Ka fragment direct from global (read once), Kb from LDS
        floatx4 acc[13];
        #pragma unroll
        for (int ct = 0; ct < 13; ct++) acc[ct] = (floatx4){0.f,0.f,0.f,0.f};
        #pragma unroll
        for (int kc = 0; kc < 2; kc++) {
            short8 af = *(const short8*)&Ka[(size_t)(rt*16 + l15)*DK_ + kc*32 + q*8];
            #pragma unroll
            for (int ct = 0; ct < 13; ct++) {
                short8 bf = *(const short8*)&lKb[(ct*16 + l15)*DK_ +
                                                 ((kc*32 + q*8) ^ ((l15 & 7) << 3))];
                acc[ct] = mfma16(af, bf, acc[ct]);
            }
        }
        // ---- softmax + a-store + P->LDS (bf16)
        #pragma unroll
        for (int r = 0; r < 4; r++) {
            int srow = rt*16 + q*4 + r;
            float v[13];
            float mx = -1e9f;
            #pragma unroll
            for (int ct = 0; ct < 13; ct++) {
                int t = ct*16 + l15;
                v[ct] = (t < S_) ? acc[ct][r]*scale : -1e9f;
                mx = fmaxf(mx, v[ct]);
            }
            #pragma unroll
            for (int off = 1; off < 16; off <<= 1) mx = fmaxf(mx, __shfl_xor(mx, off));
            float sum = 0.f;
            #pragma unroll
            for (int ct = 0; ct < 13; ct++) {
                int t = ct*16 + l15;
                float e = (t < S_) ? __expf(v[ct] - mx) : 0.f;
                v[ct] = e; sum += e;
            }
            #pragma unroll
            for (int off = 1; off < 16; off <<= 1) sum += __shfl_xor(sum, off);
            float inv = 1.0f / sum;
            bool rok = srow < S_;
            #pragma unroll
            for (int ct = 0; ct < 13; ct++) {
                int t = ct*16 + l15;
                float pv = rok ? v[ct]*inv : 0.f;
                lPw[(q*4 + r)*TPP_ + ct*16 + l15] = f2bf(pv);
                if (rok && t < S_) storeF(dout, aBase + (size_t)srow*S_ + t, pv, is32);
            }
            lPw[(q*4 + r)*TPP_ + 208 + l15] = 0;   // zero K-pad cols 208..223
        }
        // ---- PV: f rows rt*16.. = P @ V  (wave-private lP, no barrier needed)
        floatx4 facc[4];
        #pragma unroll
        for (int ct = 0; ct < 4; ct++) facc[ct] = (floatx4){0.f,0.f,0.f,0.f};
        for (int kc = 0; kc < 7; kc++) {
            short8 paf = *(const short8*)&lPw[l15*TPP_ + kc*32 + q*8];
            #pragma unroll
            for (int ct = 0; ct < 4; ct++) {
                short8 bf = *(const short8*)&lV[(ct*16 + l15)*TPP_ + kc*32 + q*8];
                facc[ct] = mfma16(paf, bf, facc[ct]);
            }
        }
        #pragma unroll
        for (int ct = 0; ct < 4; ct++)
            #pragma unroll
            for (int r = 0; r < 4; r++) {
                int so = rt*16 + q*4 + r;
                fO[(size_t)so*DK_ + ct*16 + l15] = f2bf(facc[ct][r]);
            }
    }
}

// ---------------- comb = (f0 f1^T + f1 f0^T) * scale/2 -> ws [bh][208][224]
// lf0/lf1 XOR-swizzled -> conflict-free ds_read_b128.
__global__ __launch_bounds__(256) void comb_kernel(u16* __restrict__ ws) {
    __shared__ __align__(16) u16 lf0[SP_*DK_];
    __shared__ __align__(16) u16 lf1[SP_*DK_];
    int bh = blockIdx.x;
    const u16* f0 = ws + F0_OFF + (size_t)bh*SP_*DK_;
    const u16* f1 = ws + F1_OFF + (size_t)bh*SP_*DK_;
    u16* cO = ws + COMB_OFF + (size_t)bh*SP_*TP_;
    int tid = threadIdx.x;
    for (int i = tid; i < SP_*8; i += 256) {
        int d = (i & ~7) | ((i ^ (i >> 3)) & 7);
        ((uint4v*)lf0)[d] = ((const uint4v*)f0)[i];
        ((uint4v*)lf1)[d] = ((const uint4v*)f1)[i];
    }
    __syncthreads();
    int w = tid>>6, lane = tid&63, q = lane>>4, l15 = lane&15;
    int sw = (l15 & 7) << 3;   // per-lane XOR for swizzled reads (row&7 == l15&7)
    const float cscale = 0.0625f;   // (1/8)*0.5
    for (int rt = w; rt < 13; rt += 4) {
        short8 a0f[2], a1f[2];
        #pragma unroll
        for (int kc = 0; kc < 2; kc++) {
            int eo = (kc*32 + q*8) ^ sw;
            a0f[kc] = *(const short8*)&lf0[(rt*16 + l15)*DK_ + eo];
            a1f[kc] = *(const short8*)&lf1[(rt*16 + l15)*DK_ + eo];
        }
        for (int nt = 0; nt < 13; nt++) {
            floatx4 acc = (floatx4){0.f,0.f,0.f,0.f};
            #pragma unroll
            for (int kc = 0; kc < 2; kc++) {
                short8 b1 = *(const short8*)&lf1[(nt*16 + l15)*DK_ + ((kc*32 + q*8) ^ sw)];
                acc = mfma16(a0f[kc], b1, acc);
            }
            #pragma unroll
            for (int kc = 0; kc < 2; kc++) {
                short8 b0 = *(const short8*)&lf0[(nt*16 + l15)*DK_ + ((kc*32 + q*8) ^ sw)];
                acc = mfma16(a1f[kc], b0, acc);
            }
            #pragma unroll
            for (int r = 0; r < 4; r++) {
                int srow = rt*16 + q*4 + r;
                cO[(size_t)srow*TP_ + nt*16 + l15] = f2bf(acc[r]*cscale);
            }
        }
        #pragma unroll
        for (int r = 0; r < 4; r++) {
            int srow = rt*16 + q*4 + r;
            cO[(size_t)srow*TP_ + 208 + l15] = 0;   // zero K-pad cols 208..223
        }
    }
}

// ---------------- out = comb @ wo^T + bo -> d_out [bh][197][1024]
// lw rows padded 224->232 elems: 8-way bank conflict -> 2-way (free).
__global__ __launch_bounds__(256) void out_kernel(const u16* __restrict__ ws,
                                                  void* __restrict__ dout,
                                                  const u16* __restrict__ x0det) {
    __shared__ __align__(16) u16 lw[128*TPP_];   // 58.0 KB
    int is32 = detect_f32(x0det);
    int bh = blockIdx.x, nb = blockIdx.y;
    const u16* wot = ws + WOT_OFF + (size_t)nb*128*TP_;
    const u16* cI  = ws + COMB_OFF + (size_t)bh*SP_*TP_;
    size_t oBase = (size_t)bh*S_*D_;
    int tid = threadIdx.x;
    for (int i = tid; i < 128*28; i += 256) {
        int row = i / 28, c = i - row*28;
        ((uint4v*)lw)[row*29 + c] = ((const uint4v*)wot)[i];
    }
    __syncthreads();
    int w = tid>>6, lane = tid&63, q = lane>>4, l15 = lane&15;
    for (int mt = w; mt < 13; mt += 4) {
        floatx4 acc[8];
        #pragma unroll
        for (int nt = 0; nt < 8; nt++) acc[nt] = (floatx4){0.f,0.f,0.f,0.f};
        for (int kc = 0; kc < 7; kc++) {
            short8 af = *(const short8*)&cI[(size_t)(mt*16 + l15)*TP_ + kc*32 + q*8];
            #pragma unroll
            for (int nt = 0; nt < 8; nt++) {
                short8 bf = *(const short8*)&lw[(nt*16 + l15)*TPP_ + kc*32 + q*8];
                acc[nt] = mfma16(af, bf, acc[nt]);
            }
        }
        #pragma unroll
        for (int nt = 0; nt < 8; nt++) {
            int d = nb*128 + nt*16 + l15;
            float bv = bf2f(ws[BIAS_OFF + 4*1024 + d]);
            #pragma unroll
            for (int r = 0; r < 4; r++) {
                int s = mt*16 + q*4 + r;
                if (s < S_) storeF(dout, oBase + (size_t)s*D_ + d, acc[nt][r] + bv, is32);
            }
        }
    }
}

extern "C" void kernel_launch(void* const* d_in, const int* in_sizes, int n_in,
                              void* d_out, int out_size, void* d_ws, size_t ws_size,
                              hipStream_t stream) {
    const void* x0  = d_in[0];
    const void* x1  = d_in[1];
    const void* wk0 = d_in[2];
    const void* bk0 = d_in[3];
    const void* wk1 = d_in[4];
    const void* bk1 = d_in[5];
    const void* wv0 = d_in[6];
    const void* bv0 = d_in[7];
    const void* wv1 = d_in[8];
    const void* bv1 = d_in[9];
    const void* wo  = d_in[10];
    const void* bo  = d_in[11];
    u16* ws = (u16*)d_ws;
    const u16* x0det = (const u16*)x0;

    if (ws_size < WS_ELEMS * sizeof(u16)) return;

    prep_kernel<<<3456, 256, 0, stream>>>(wo, bk0, bk1, bv0, bv1, bo,
                                          x0, x1, wk0, wk1, wv0, wv1, ws);
    proj_kernel<<<dim3(50, 8, 4), 256, 0, stream>>>(ws);
    attn_av_kernel<<<dim3(BH_, 2), 256, 0, stream>>>(ws, d_out, x0det);
    comb_kernel<<<BH_, 256, 0, stream>>>(ws);
    out_kernel<<<dim3(BH_, 8), 256, 0, stream>>>(ws, d_out, x0det);
}

// Round 3
// 1070.860 us; speedup vs baseline: 1.0270x; 1.0270x over previous
//
#include <hip/hip_runtime.h>
#include <hip/hip_bf16.h>

typedef unsigned short u16;
typedef __attribute__((ext_vector_type(8))) short short8;
typedef __attribute__((ext_vector_type(4))) float floatx4;
typedef __attribute__((ext_vector_type(4), aligned(4))) float floatx4u;  // 4B-aligned vector load
typedef __attribute__((ext_vector_type(4))) unsigned int uint4v;

#define B_ 32
#define S_ 197
#define D_ 1024
#define H_ 16
#define DK_ 64
#define BH_ 512
#define SP_ 208   // S padded to 13*16 (row tiles)
#define TP_ 224   // S padded to 7*32 (K-dim tiles)
#define TPP_ 232  // TP_ padded for LDS bank spread (464B rows, 16B-aligned, 2-way only)
#define M_ 6304   // B*S
#define XSZ_ ((size_t)M_*D_)        // 6,455,296 elems per x
#define WSZ_W ((size_t)D_*D_)       // 1,048,576 elems per weight

// workspace layout (bf16 element offsets)
#define KSZ ((size_t)BH_*SP_*DK_)   // 6,815,744
#define VSZ ((size_t)BH_*DK_*TP_)   // 7,340,032
#define CSZ ((size_t)BH_*SP_*TP_)   // 23,855,104
#define K0_OFF  ((size_t)0)
#define K1_OFF  (KSZ)
#define VT0_OFF (2*KSZ)
#define VT1_OFF (2*KSZ + VSZ)
#define F0_OFF  (2*KSZ + 2*VSZ)
#define F1_OFF  (3*KSZ + 2*VSZ)
#define COMB_OFF (4*KSZ + 2*VSZ)
#define WOT_OFF  (4*KSZ + 2*VSZ + CSZ)
#define BIAS_OFF (WOT_OFF + (size_t)D_*TP_)   // bk0|bk1|bv0|bv1|bo, 1024 each, bf16
#define WS_ELEMS (BIAS_OFF + 5*1024)

// bf16 staging of inputs lives in the COMB region (dead: comb now stays in LDS)
#define XB_OFF  (COMB_OFF)
#define WB_OFF  (COMB_OFF + 2*XSZ_)

// d_out layout (elements of the output dtype): out | a0 | a1
#define OUT_SZ ((size_t)BH_*S_*D_)   // 103,284,736
#define A_SZ   ((size_t)BH_*S_*S_)   // 19,870,208

__device__ __forceinline__ float bf2f(u16 v) {
    unsigned u = ((unsigned)v) << 16;
    return __builtin_bit_cast(float, u);
}
__device__ __forceinline__ u16 f2bf(float f) {
    unsigned u = __builtin_bit_cast(unsigned, f);
    u += 0x7FFFu + ((u >> 16) & 1u);   // RNE
    return (u16)(u >> 16);
}
__device__ __forceinline__ floatx4 mfma16(short8 a, short8 b, floatx4 c) {
    return __builtin_amdgcn_mfma_f32_16x16x32_bf16(a, b, c, 0, 0, 0);
}
// async global->LDS, 16B per lane; lds dest is wave-uniform base + lane*16
__device__ __forceinline__ void gl_lds16(const u16* g, u16* l) {
    __builtin_amdgcn_global_load_lds(
        (const __attribute__((address_space(1))) void*)(g),
        (__attribute__((address_space(3))) void*)(l), 16, 0, 0);
}

// Runtime input-dtype detection (see previous rounds): deterministic, cheap.
__device__ __forceinline__ int detect_f32(const u16* __restrict__ x0raw) {
    int lane = threadIdx.x & 63;
    unsigned h = x0raw[2*lane];
    unsigned e = (h >> 7) & 0xFFu;
    int ext = (e < 0x30u) | (e > 0x4Fu);
    unsigned long long m = __ballot(ext);
    return __popcll(m) > 16;
}

// dtype-flexible element accessors
__device__ __forceinline__ u16 loadBF(const void* p, size_t off, int is32) {
    return is32 ? f2bf(((const float*)p)[off]) : ((const u16*)p)[off];
}
__device__ __forceinline__ void storeF(void* p, size_t off, float v, int is32) {
    if (is32) ((float*)p)[off] = v; else ((u16*)p)[off] = f2bf(v);
}
// 8 contiguous elements -> bf16 bits (aligned: off multiple of 8)
__device__ __forceinline__ short8 load8(const void* p, size_t off, int is32) {
    short8 r;
    if (is32) {
        const float* f = (const float*)p + off;
        floatx4 a = *(const floatx4*)f;
        floatx4 b = *(const floatx4*)(f + 4);
        r[0]=(short)f2bf(a[0]); r[1]=(short)f2bf(a[1]);
        r[2]=(short)f2bf(a[2]); r[3]=(short)f2bf(a[3]);
        r[4]=(short)f2bf(b[0]); r[5]=(short)f2bf(b[1]);
        r[6]=(short)f2bf(b[2]); r[7]=(short)f2bf(b[3]);
    } else {
        r = *(const short8*)((const u16*)p + off);
    }
    return r;
}

// ---------------- prep: wot zero-padded; zero K/Vt pads; biases; bf16-convert inputs
__global__ __launch_bounds__(256) void prep_kernel(
    const void* __restrict__ wo,
    const void* __restrict__ bk0, const void* __restrict__ bk1,
    const void* __restrict__ bv0, const void* __restrict__ bv1,
    const void* __restrict__ bo,
    const void* __restrict__ x0, const void* __restrict__ x1,
    const void* __restrict__ wk0, const void* __restrict__ wk1,
    const void* __restrict__ wv0, const void* __restrict__ wv1,
    u16* __restrict__ ws) {
    int is32 = detect_f32((const u16*)x0);
    int i = blockIdx.x * 256 + threadIdx.x;
    if (i < D_*TP_) {
        int d = i / TP_, t = i - d*TP_;
        ws[WOT_OFF + i] = (t < S_) ? loadBF(wo, (size_t)d*S_ + t, is32) : (u16)0;
    }
    const int KP = BH_*(SP_-S_)*DK_;   // 360448
    if (i < KP) {
        int bh = i / ((SP_-S_)*DK_);
        int r  = i - bh*((SP_-S_)*DK_);
        int s  = S_ + r / DK_;
        int dk = r % DK_;
        size_t o = ((size_t)bh*SP_ + s)*DK_ + dk;
        ws[K0_OFF + o] = 0; ws[K1_OFF + o] = 0;
    }
    const int VP = BH_*DK_*(TP_-S_);   // 884736
    if (i < VP) {
        int bh = i / (DK_*(TP_-S_));
        int r  = i - bh*(DK_*(TP_-S_));
        int dk = r / (TP_-S_);
        int t  = S_ + r % (TP_-S_);
        size_t o = ((size_t)bh*DK_ + dk)*TP_ + t;
        ws[VT0_OFF + o] = 0; ws[VT1_OFF + o] = 0;
    }
    if (i < 5*1024) {
        int which = i >> 10, j = i & 1023;
        const void* src = (which==0) ? bk0 : (which==1) ? bk1
                        : (which==2) ? bv0 : (which==3) ? bv1 : bo;
        ws[BIAS_OFF + i] = loadBF(src, j, is32);
    }
    // grid-stride bf16 conversion: 2*XSZ_ x-elems + 4*WSZ_W weight-elems, 8 at a time
    const size_t NCH = (2*XSZ_ + 4*WSZ_W) / 8;   // 2,138,112 chunks
    for (size_t c = (size_t)blockIdx.x*256 + threadIdx.x; c < NCH;
         c += (size_t)gridDim.x*256) {
        size_t e = c * 8;
        const void* src; size_t soff;
        if (e < 2*XSZ_) {
            src = (e < XSZ_) ? x0 : x1;
            soff = (e < XSZ_) ? e : e - XSZ_;
        } else {
            size_t r = e - 2*XSZ_;
            int z = (int)(r >> 20);            // WSZ_W = 2^20
            src = (z==0) ? wk0 : (z==1) ? wk1 : (z==2) ? wv0 : wv1;
            soff = r & (WSZ_W - 1);
        }
        *(short8*)&ws[XB_OFF + e] = load8(src, soff, is32);
    }
}

// ---------------- projections: C = x@W^T + b -> K [bh][208][64] or Vt [bh][64][224]
// m97 structure + XCD-aware bijective swizzle: 1600 blocks, 200/XCD chunks so the
// 50 consecutive blocks sharing one 256KB W-tile land on the same XCD L2.
__global__ __launch_bounds__(256) void proj_kernel(u16* __restrict__ ws)
{
    __shared__ __align__(16) u16 lA[128*64];
    __shared__ __align__(16) u16 lB[128*64];
    int L = blockIdx.x;
    int o = (L & 7) * 200 + (L >> 3);   // bijective: nwg=1600, 1600%8==0
    int bx = o % 50;
    int yz = o / 50;
    int by = yz & 7;
    int z  = yz >> 3;
    const u16* X = ws + XB_OFF + (size_t)(z & 1)*XSZ_;
    const u16* W = ws + WB_OFF + (size_t)z*WSZ_W;
    u16* dst = ws + ((z==0) ? K0_OFF : (z==1) ? K1_OFF : (z==2) ? VT0_OFF : VT1_OFF);
    int m0 = bx * 128, n0 = by * 128;
    int tid = threadIdx.x;
    int w = tid >> 6, lane = tid & 63, q = lane >> 4, l15 = lane & 15;
    int wm = (w >> 1) * 64, wn = (w & 1) * 64;

    floatx4 acc[4][4];
    #pragma unroll
    for (int a = 0; a < 4; a++)
        #pragma unroll
        for (int b = 0; b < 4; b++) acc[a][b] = (floatx4){0.f,0.f,0.f,0.f};

    for (int kk = 0; kk < D_; kk += 64) {
        __syncthreads();
        #pragma unroll
        for (int it = 0; it < 4; it++) {
            int c = it*256 + w*64 + lane;   // chunk of 8 elems; lane-linear = LDS-linear
            int r = c >> 3, cc = c & 7;
            int m = m0 + r; if (m > M_-1) m = M_-1;
            gl_lds16(X + (size_t)m*D_ + kk + cc*8,        &lA[(it*256 + w*64)*8]);
            gl_lds16(W + (size_t)(n0 + r)*D_ + kk + cc*8, &lB[(it*256 + w*64)*8]);
        }
        __syncthreads();   // drains vmcnt before ds_read
        #pragma unroll
        for (int kc = 0; kc < 2; kc++) {
            short8 af[4], bf[4];
            #pragma unroll
            for (int mi = 0; mi < 4; mi++)
                af[mi] = *(const short8*)&lA[(wm + mi*16 + l15)*64 + kc*32 + q*8];
            #pragma unroll
            for (int ni = 0; ni < 4; ni++)
                bf[ni] = *(const short8*)&lB[(wn + ni*16 + l15)*64 + kc*32 + q*8];
            #pragma unroll
            for (int mi = 0; mi < 4; mi++)
                #pragma unroll
                for (int ni = 0; ni < 4; ni++)
                    acc[mi][ni] = mfma16(af[mi], bf[ni], acc[mi][ni]);
        }
    }
    #pragma unroll
    for (int ni = 0; ni < 4; ni++) {
        int n = n0 + wn + ni*16 + l15;
        float bv = bf2f(ws[BIAS_OFF + (size_t)z*1024 + n]);
        int h = n >> 6, dk = n & 63;
        #pragma unroll
        for (int mi = 0; mi < 4; mi++)
            #pragma unroll
            for (int r = 0; r < 4; r++) {
                int m = m0 + wm + mi*16 + q*4 + r;
                if (m < M_) {
                    int b = m / S_;
                    int s = m - b * S_;
                    int bh = b * H_ + h;
                    size_t o2 = (z < 2) ? (((size_t)bh*SP_ + s)*DK_ + dk)
                                        : (((size_t)bh*DK_ + dk)*TP_ + s);
                    dst[o2] = f2bf(acc[mi][ni][r] + bv);
                }
            }
    }
}

// ---------------- fused scores+softmax+AV:
//   a_dir = softmax_rows(Ka @ Kb^T * scale) -> d_out (f32/bf16)
//   f_dir = a_dir @ V_dir -> ws F (bf16), P routed through per-wave LDS tile.
// V fragments read DIRECT from global (single-use, L2-resident; staging was pure
// overhead and pushed LDS to 84KB -> 1 block/CU). LDS now 55KB -> 2 blocks/CU.
__global__ __launch_bounds__(256) void attn_av_kernel(u16* __restrict__ ws,
                                                      void* __restrict__ dout,
                                                      const u16* __restrict__ x0det) {
    __shared__ __align__(16) u16 lKb[SP_*DK_];      // 26.0 KB, XOR-swizzled
    __shared__ __align__(16) u16 lP[4][16*TPP_];    // 29.0 KB, per-wave P tile
    int is32 = detect_f32(x0det);
    int bh = blockIdx.x, dir = blockIdx.y;
    const u16* Ka = ws + (dir ? K1_OFF : K0_OFF) + (size_t)bh*SP_*DK_;
    const u16* Kb = ws + (dir ? K0_OFF : K1_OFF) + (size_t)bh*SP_*DK_;
    const u16* Vt = ws + (dir ? VT1_OFF : VT0_OFF) + (size_t)bh*DK_*TP_;
    u16* fO = ws + (dir ? F1_OFF : F0_OFF) + (size_t)bh*SP_*DK_;
    size_t aBase = OUT_SZ + (size_t)dir*A_SZ + (size_t)bh*S_*S_;
    int tid = threadIdx.x;
    // stage Kb with XOR swizzle: chunk i (row=i>>3, c=i&7) -> row*8 + (c ^ (row&7))
    for (int i = tid; i < SP_*8; i += 256)
        ((uint4v*)lKb)[(i & ~7) | ((i ^ (i >> 3)) & 7)] = ((const uint4v*)Kb)[i];
    __syncthreads();
    int w = tid>>6, lane = tid&63, q = lane>>4, l15 = lane&15;
    u16* lPw = &lP[w][0];
    const float scale = 0.125f;
    for (int rt = w; rt < 13; rt += 4) {
        // ---- scores: Ka fragment direct from global (read once), Kb from LDS
        floatx4 acc[13];
        #pragma unroll
        for (int ct = 0; ct < 13; ct++) acc[ct] = (floatx4){0.f,0.f,0.f,0.f};
        #pragma unroll
        for (int kc = 0; kc < 2; kc++) {
            short8 af = *(const short8*)&Ka[(size_t)(rt*16 + l15)*DK_ + kc*32 + q*8];
            #pragma unroll
            for (int ct = 0; ct < 13; ct++) {
                short8 bf = *(const short8*)&lKb[(ct*16 + l15)*DK_ +
                                                 ((kc*32 + q*8) ^ ((l15 & 7) << 3))];
                acc[ct] = mfma16(af, bf, acc[ct]);
            }
        }
        // ---- softmax + a-store + P->LDS (bf16)
        #pragma unroll
        for (int r = 0; r < 4; r++) {
            int srow = rt*16 + q*4 + r;
            float v[13];
            float mx = -1e9f;
            #pragma unroll
            for (int ct = 0; ct < 13; ct++) {
                int t = ct*16 + l15;
                v[ct] = (t < S_) ? acc[ct][r]*scale : -1e9f;
                mx = fmaxf(mx, v[ct]);
            }
            #pragma unroll
            for (int off = 1; off < 16; off <<= 1) mx = fmaxf(mx, __shfl_xor(mx, off));
            float sum = 0.f;
            #pragma unroll
            for (int ct = 0; ct < 13; ct++) {
                int t = ct*16 + l15;
                float e = (t < S_) ? __expf(v[ct] - mx) : 0.f;
                v[ct] = e; sum += e;
            }
            #pragma unroll
            for (int off = 1; off < 16; off <<= 1) sum += __shfl_xor(sum, off);
            float inv = 1.0f / sum;
            bool rok = srow < S_;
            #pragma unroll
            for (int ct = 0; ct < 13; ct++) {
                int t = ct*16 + l15;
                float pv = rok ? v[ct]*inv : 0.f;
                lPw[(q*4 + r)*TPP_ + ct*16 + l15] = f2bf(pv);
                if (rok && t < S_) storeF(dout, aBase + (size_t)srow*S_ + t, pv, is32);
            }
            lPw[(q*4 + r)*TPP_ + 208 + l15] = 0;   // zero K-pad cols 208..223
        }
        // ---- PV: f rows rt*16.. = P @ V  (wave-private lP; V direct from global)
        floatx4 facc[4];
        #pragma unroll
        for (int ct = 0; ct < 4; ct++) facc[ct] = (floatx4){0.f,0.f,0.f,0.f};
        for (int kc = 0; kc < 7; kc++) {
            short8 paf = *(const short8*)&lPw[l15*TPP_ + kc*32 + q*8];
            #pragma unroll
            for (int ct = 0; ct < 4; ct++) {
                short8 bf = *(const short8*)&Vt[(size_t)(ct*16 + l15)*TP_ + kc*32 + q*8];
                facc[ct] = mfma16(paf, bf, facc[ct]);
            }
        }
        #pragma unroll
        for (int ct = 0; ct < 4; ct++)
            #pragma unroll
            for (int r = 0; r < 4; r++) {
                int so = rt*16 + q*4 + r;
                fO[(size_t)so*DK_ + ct*16 + l15] = f2bf(facc[ct][r]);
            }
    }
}

// ---------------- fused comb+out per bh (512 threads, 8 waves):
//   comb = (f0 f1^T + f1 f0^T)*cscale  -> LDS lC [208][232]  (no HBM round-trip)
//   out  = comb @ wo^T + bo            -> d_out [bh][197][1024], 8 wo-tiles of 128
// LDS aliasing: smem = lC (94.4KB) | region2 (59.4KB). region2 holds lf0+lf1
// (52KB, phases A/B) then lw (59.4KB, phase C). Peak 152.2KB < 160KB.
__global__ __launch_bounds__(512) void comb_out_kernel(const u16* __restrict__ ws,
                                                       void* __restrict__ dout,
                                                       const u16* __restrict__ x0det) {
    __shared__ __align__(16) u16 smem[SP_*TPP_ + 128*TPP_];   // 77,952 u16 = 152.3 KB
    u16* lC  = smem;                    // [208][232]
    u16* lw  = smem + SP_*TPP_;         // [128][232] phase C
    u16* lf0 = lw;                      // [208][64] swizzled, phases A/B
    u16* lf1 = lw + SP_*DK_;
    int is32 = detect_f32(x0det);
    int bh = blockIdx.x;
    const u16* f0 = ws + F0_OFF + (size_t)bh*SP_*DK_;
    const u16* f1 = ws + F1_OFF + (size_t)bh*SP_*DK_;
    size_t oBase = (size_t)bh*S_*D_;
    int tid = threadIdx.x;
    // ---- phase A: stage f0/f1 with XOR swizzle
    for (int i = tid; i < SP_*8; i += 512) {
        int d = (i & ~7) | ((i ^ (i >> 3)) & 7);
        ((uint4v*)lf0)[d] = ((const uint4v*)f0)[i];
        ((uint4v*)lf1)[d] = ((const uint4v*)f1)[i];
    }
    __syncthreads();
    int w = tid>>6, lane = tid&63, q = lane>>4, l15 = lane&15;
    int sw = (l15 & 7) << 3;   // per-lane XOR for swizzled reads (row&7 == l15&7)
    const float cscale = 0.0625f;   // (1/8)*0.5
    // ---- phase B: comb -> lC
    for (int rt = w; rt < 13; rt += 8) {
        short8 a0f[2], a1f[2];
        #pragma unroll
        for (int kc = 0; kc < 2; kc++) {
            int eo = (kc*32 + q*8) ^ sw;
            a0f[kc] = *(const short8*)&lf0[(rt*16 + l15)*DK_ + eo];
            a1f[kc] = *(const short8*)&lf1[(rt*16 + l15)*DK_ + eo];
        }
        for (int nt = 0; nt < 13; nt++) {
            floatx4 acc = (floatx4){0.f,0.f,0.f,0.f};
            #pragma unroll
            for (int kc = 0; kc < 2; kc++) {
                short8 b1 = *(const short8*)&lf1[(nt*16 + l15)*DK_ + ((kc*32 + q*8) ^ sw)];
                acc = mfma16(a0f[kc], b1, acc);
            }
            #pragma unroll
            for (int kc = 0; kc < 2; kc++) {
                short8 b0 = *(const short8*)&lf0[(nt*16 + l15)*DK_ + ((kc*32 + q*8) ^ sw)];
                acc = mfma16(a1f[kc], b0, acc);
            }
            #pragma unroll
            for (int r = 0; r < 4; r++) {
                int srow = rt*16 + q*4 + r;
                lC[srow*TPP_ + nt*16 + l15] = f2bf(acc[r]*cscale);
            }
        }
        #pragma unroll
        for (int r = 0; r < 4; r++) {
            int srow = rt*16 + q*4 + r;
            lC[srow*TPP_ + 208 + l15] = 0;   // zero K-pad cols 208..223
        }
    }
    __syncthreads();   // lC complete; lf region now dead -> reuse as lw
    // ---- phase C: out = lC @ wo^T + bo, 8 tiles of 128 output cols
    for (int nb = 0; nb < 8; nb++) {
        const u16* wot = ws + WOT_OFF + (size_t)nb*128*TP_;
        for (int i = tid; i < 128*28; i += 512) {
            int row = i / 28, c = i - row*28;
            ((uint4v*)lw)[row*29 + c] = ((const uint4v*)wot)[i];
        }
        __syncthreads();
        for (int mt = w; mt < 13; mt += 8) {
            floatx4 acc[8];
            #pragma unroll
            for (int nt = 0; nt < 8; nt++) acc[nt] = (floatx4){0.f,0.f,0.f,0.f};
            for (int kc = 0; kc < 7; kc++) {
                short8 af = *(const short8*)&lC[(mt*16 + l15)*TPP_ + kc*32 + q*8];
                #pragma unroll
                for (int nt = 0; nt < 8; nt++) {
                    short8 bf = *(const short8*)&lw[(nt*16 + l15)*TPP_ + kc*32 + q*8];
                    acc[nt] = mfma16(af, bf, acc[nt]);
                }
            }
            #pragma unroll
            for (int nt = 0; nt < 8; nt++) {
                int d = nb*128 + nt*16 + l15;
                float bv = bf2f(ws[BIAS_OFF + 4*1024 + d]);
                #pragma unroll
                for (int r = 0; r < 4; r++) {
                    int s = mt*16 + q*4 + r;
                    if (s < S_) storeF(dout, oBase + (size_t)s*D_ + d, acc[nt][r] + bv, is32);
                }
            }
        }
        __syncthreads();   // all reads of lw done before next tile overwrites it
    }
}

extern "C" void kernel_launch(void* const* d_in, const int* in_sizes, int n_in,
                              void* d_out, int out_size, void* d_ws, size_t ws_size,
                              hipStream_t stream) {
    const void* x0  = d_in[0];
    const void* x1  = d_in[1];
    const void* wk0 = d_in[2];
    const void* bk0 = d_in[3];
    const void* wk1 = d_in[4];
    const void* bk1 = d_in[5];
    const void* wv0 = d_in[6];
    const void* bv0 = d_in[7];
    const void* wv1 = d_in[8];
    const void* bv1 = d_in[9];
    const void* wo  = d_in[10];
    const void* bo  = d_in[11];
    u16* ws = (u16*)d_ws;
    const u16* x0det = (const u16*)x0;

    if (ws_size < WS_ELEMS * sizeof(u16)) return;

    prep_kernel<<<3456, 256, 0, stream>>>(wo, bk0, bk1, bv0, bv1, bo,
                                          x0, x1, wk0, wk1, wv0, wv1, ws);
    proj_kernel<<<1600, 256, 0, stream>>>(ws);
    attn_av_kernel<<<dim3(BH_, 2), 256, 0, stream>>>(ws, d_out, x0det);
    comb_out_kernel<<<BH_, 512, 0, stream>>>(ws, d_out, x0det);
}